// Round 3
// baseline (1506.116 us; speedup 1.0000x reference)
//
#include <hip/hip_runtime.h>

#define PP 64      // context positions (softmax dim)
#define KD 128     // feature dim
#define KC 32      // sigma k-chunk rows per stage
#define SROW 132   // padded LDS row stride for shifted (132%32=4 -> 2-way alias = free)

// One block per m. t = S * Sigma (64x128 @ 128x128), score[p] = -dot(t[p],S[p]),
// softmax over p. Single sigma LDS buffer + register prefetch (51 KB LDS ->
// 3 blocks/CU). Inner loop restructured to ~90 live VGPRs to avoid the
// round-2 scratch spill (3.26 GB of spill writes at VGPR cap 128).
__global__ __launch_bounds__(256, 2)
void quadform_softmax(const float* __restrict__ color,
                      const float* __restrict__ mew,
                      const float* __restrict__ sigma,
                      float* __restrict__ out) {
  __shared__ __align__(16) float s_lds[PP * SROW];    // 33792 B shifted
  __shared__ __align__(16) float sig_lds[KC * KD];    // 16384 B sigma chunk
  __shared__ __align__(16) float mew_lds[KD];
  __shared__ float scores_lds[PP];

  const int m = blockIdx.x;
  const int tid = threadIdx.x;

  const float4* c4 = reinterpret_cast<const float4*>(color + (size_t)m * (PP * KD));
  const float4* g4 = reinterpret_cast<const float4*>(sigma + (size_t)m * (KD * KD));

  if (tid < 32) {
    reinterpret_cast<float4*>(mew_lds)[tid] =
        reinterpret_cast<const float4*>(mew + (size_t)m * KD)[tid];
  }
  // sigma chunk 0 -> registers while mew barrier settles (16 VGPRs, short-lived)
  float4 sreg[4];
#pragma unroll
  for (int i = 0; i < 4; ++i) sreg[i] = g4[i * 256 + tid];
  __syncthreads();  // mew ready

  // stream shifted = color - mew -> LDS (1 float4 live at a time)
#pragma unroll
  for (int i = 0; i < 8; ++i) {
    float4 v = c4[i * 256 + tid];
    int flat = i * 1024 + tid * 4;  // element index in 64x128
    int p = flat >> 7;
    int k = flat & 127;
    float4 mv = *reinterpret_cast<const float4*>(&mew_lds[k]);
    v.x -= mv.x; v.y -= mv.y; v.z -= mv.z; v.w -= mv.w;
    *reinterpret_cast<float4*>(&s_lds[p * SROW + k]) = v;
  }
#pragma unroll
  for (int i = 0; i < 4; ++i)
    *reinterpret_cast<float4*>(&sig_lds[i * 1024 + tid * 4]) = sreg[i];
  __syncthreads();

  // ---- main GEMM: thread tile 4 p-rows x 8 l-cols (l = tx*4 and tx*4+64) ----
  const int ty = tid >> 4;   // 0..15
  const int tx = tid & 15;   // 0..15
  const int p0 = ty * 4;
  const int l0 = tx * 4;

  float acc[4][8];
#pragma unroll
  for (int i = 0; i < 4; ++i)
#pragma unroll
    for (int j = 0; j < 8; ++j) acc[i][j] = 0.f;

#pragma unroll 1   // keep chunk loop rolled: unrolled body ~9 KB, stay under I$
  for (int c = 0; c < 4; ++c) {
    // register prefetch of next sigma chunk (16 VGPRs live across compute)
    float4 nreg[4];
    if (c < 3) {
#pragma unroll
      for (int i = 0; i < 4; ++i) nreg[i] = g4[(c + 1) * 1024 + i * 256 + tid];
    }
    const int kbase = c * KC;
#pragma unroll
    for (int kk = 0; kk < KC; kk += 4) {
      float as[4][4];  // 16 VGPRs
#pragma unroll
      for (int i = 0; i < 4; ++i) {
        float4 t = *reinterpret_cast<const float4*>(
            &s_lds[(p0 + i) * SROW + kbase + kk]);
        as[i][0] = t.x; as[i][1] = t.y; as[i][2] = t.z; as[i][3] = t.w;
      }
#pragma unroll
      for (int d = 0; d < 4; ++d) {
        // only 8 B-regs live at a time (was 32 -> spilled)
        float4 blo = *reinterpret_cast<const float4*>(&sig_lds[(kk + d) * KD + l0]);
        float4 bhi = *reinterpret_cast<const float4*>(&sig_lds[(kk + d) * KD + l0 + 64]);
#pragma unroll
        for (int i = 0; i < 4; ++i) {
          const float av = as[i][d];
          acc[i][0] = fmaf(av, blo.x, acc[i][0]);
          acc[i][1] = fmaf(av, blo.y, acc[i][1]);
          acc[i][2] = fmaf(av, blo.z, acc[i][2]);
          acc[i][3] = fmaf(av, blo.w, acc[i][3]);
          acc[i][4] = fmaf(av, bhi.x, acc[i][4]);
          acc[i][5] = fmaf(av, bhi.y, acc[i][5]);
          acc[i][6] = fmaf(av, bhi.z, acc[i][6]);
          acc[i][7] = fmaf(av, bhi.w, acc[i][7]);
        }
      }
    }
    __syncthreads();  // all reads of sig_lds complete
    if (c < 3) {
#pragma unroll
      for (int i = 0; i < 4; ++i)
        *reinterpret_cast<float4*>(&sig_lds[i * 1024 + tid * 4]) = nreg[i];
      __syncthreads();  // next chunk ready
    }
  }

  // ---- epilogue: score[p] = -sum_l t[p,l]*s[p,l] ----
  float part[4];
#pragma unroll
  for (int i = 0; i < 4; ++i) {
    float4 sv0 = *reinterpret_cast<const float4*>(&s_lds[(p0 + i) * SROW + l0]);
    float4 sv1 = *reinterpret_cast<const float4*>(&s_lds[(p0 + i) * SROW + l0 + 64]);
    part[i] = acc[i][0] * sv0.x + acc[i][1] * sv0.y + acc[i][2] * sv0.z + acc[i][3] * sv0.w
            + acc[i][4] * sv1.x + acc[i][5] * sv1.y + acc[i][6] * sv1.z + acc[i][7] * sv1.w;
  }
  // reduce across the 16 tx-lanes sharing each p (contiguous lanes in a wave)
#pragma unroll
  for (int off = 1; off < 16; off <<= 1) {
#pragma unroll
    for (int i = 0; i < 4; ++i) part[i] += __shfl_xor(part[i], off, 64);
  }
  if (tx == 0) {
#pragma unroll
    for (int i = 0; i < 4; ++i) scores_lds[p0 + i] = -part[i];
  }
  __syncthreads();

  // ---- softmax over the 64 scores (single wave) ----
  if (tid < 64) {
    float sc = scores_lds[tid];
    float mx = sc;
#pragma unroll
    for (int off = 1; off < 64; off <<= 1) mx = fmaxf(mx, __shfl_xor(mx, off, 64));
    float e = __expf(sc - mx);
    float s = e;
#pragma unroll
    for (int off = 1; off < 64; off <<= 1) s += __shfl_xor(s, off, 64);
    out[(size_t)m * PP + tid] = e / s;
  }
}

extern "C" void kernel_launch(void* const* d_in, const int* in_sizes, int n_in,
                              void* d_out, int out_size, void* d_ws, size_t ws_size,
                              hipStream_t stream) {
  const float* color = (const float*)d_in[0];   // (M,64,128) fp32
  const float* mew   = (const float*)d_in[1];   // (M,128)    fp32
  const float* sigma = (const float*)d_in[2];   // (M,128,128) fp32
  float* out = (float*)d_out;                   // (M,64) fp32
  const int M = in_sizes[1] / KD;
  quadform_softmax<<<M, 256, 0, stream>>>(color, mew, sigma, out);
}

// Round 4
// 1450.713 us; speedup vs baseline: 1.0382x; 1.0382x over previous
//
#include <hip/hip_runtime.h>

#define PP 64      // context positions (softmax dim)
#define KD 128     // feature dim
#define KC 32      // sigma k-chunk rows per stage
#define SROW 132   // padded LDS row stride: 132%32=4 -> A-reads 2-way bank alias (free)

// One block per m. t = S * Sigma (64x128 @ 128x128), score[p] = -dot(t[p],S[p]),
// softmax over p.
// Round-4 rewrite: NO local arrays anywhere in the hot path (rounds 2-3 showed
// acc[][]/as[][] never promoted out of scratch -> 4.9 GB of scratch HBM traffic,
// VALUBusy 7%). Everything is named float4 registers, macro-expanded.
// Thread ty owns p-rows {ty, ty+16, ty+32, ty+48} so A-row LDS reads land on
// banks 4*ty%32 (2-way alias, free) instead of the old 8-way.

#define QF_FMA4(ACC, S, B)              \
  ACC.x = fmaf((S), (B).x, ACC.x);      \
  ACC.y = fmaf((S), (B).y, ACC.y);      \
  ACC.z = fmaf((S), (B).z, ACC.z);      \
  ACC.w = fmaf((S), (B).w, ACC.w);

#define QF_STEP(D, S0, S1, S2, S3)                                                   \
  {                                                                                  \
    float4 blo = *reinterpret_cast<const float4*>(&sig_lds[(kk + (D)) * KD + l0]);   \
    float4 bhi = *reinterpret_cast<const float4*>(&sig_lds[(kk + (D)) * KD + l0 + 64]);\
    QF_FMA4(acc0l, S0, blo) QF_FMA4(acc0h, S0, bhi)                                  \
    QF_FMA4(acc1l, S1, blo) QF_FMA4(acc1h, S1, bhi)                                  \
    QF_FMA4(acc2l, S2, blo) QF_FMA4(acc2h, S2, bhi)                                  \
    QF_FMA4(acc3l, S3, blo) QF_FMA4(acc3h, S3, bhi)                                  \
  }

__global__ __launch_bounds__(256, 2)
void quadform_softmax(const float* __restrict__ color,
                      const float* __restrict__ mew,
                      const float* __restrict__ sigma,
                      float* __restrict__ out) {
  __shared__ __align__(16) float s_lds[PP * SROW];    // 33792 B shifted
  __shared__ __align__(16) float sig_lds[KC * KD];    // 16384 B sigma chunk
  __shared__ __align__(16) float mew_lds[KD];
  __shared__ float scores_lds[PP];

  const int m = blockIdx.x;
  const int tid = threadIdx.x;

  const float4* c4 = reinterpret_cast<const float4*>(color + (size_t)m * (PP * KD));
  const float4* g4 = reinterpret_cast<const float4*>(sigma + (size_t)m * (KD * KD));

  if (tid < 32) {
    reinterpret_cast<float4*>(mew_lds)[tid] =
        reinterpret_cast<const float4*>(mew + (size_t)m * KD)[tid];
  }
  // sigma chunk 0 prefetch (4 named float4, short-lived)
  float4 sg0 = g4[tid], sg1 = g4[256 + tid], sg2 = g4[512 + tid], sg3 = g4[768 + tid];
  __syncthreads();  // mew ready

  // stream shifted = color - mew -> LDS (one float4 live at a time)
#pragma unroll
  for (int i = 0; i < 8; ++i) {
    float4 v = c4[i * 256 + tid];
    int flat = i * 1024 + tid * 4;  // element index in 64x128
    int p = flat >> 7;
    int k = flat & 127;
    float4 mv = *reinterpret_cast<const float4*>(&mew_lds[k]);
    v.x -= mv.x; v.y -= mv.y; v.z -= mv.z; v.w -= mv.w;
    *reinterpret_cast<float4*>(&s_lds[p * SROW + k]) = v;
  }
  {
    float4* sdst = reinterpret_cast<float4*>(&sig_lds[tid * 4]);
    sdst[0] = sg0; sdst[256] = sg1; sdst[512] = sg2; sdst[768] = sg3;
  }
  __syncthreads();

  // ---- main GEMM: thread owns p-rows {ty,ty+16,ty+32,ty+48} x l-cols {l0..l0+3, l0+64..l0+67}
  const int ty = tid >> 4;   // 0..15
  const int tx = tid & 15;   // 0..15
  const int l0 = tx * 4;

  float4 acc0l = {0,0,0,0}, acc0h = {0,0,0,0};
  float4 acc1l = {0,0,0,0}, acc1h = {0,0,0,0};
  float4 acc2l = {0,0,0,0}, acc2h = {0,0,0,0};
  float4 acc3l = {0,0,0,0}, acc3h = {0,0,0,0};

  const float* arow0 = &s_lds[(ty     ) * SROW];
  const float* arow1 = &s_lds[(ty + 16) * SROW];
  const float* arow2 = &s_lds[(ty + 32) * SROW];
  const float* arow3 = &s_lds[(ty + 48) * SROW];

#pragma unroll 1   // keep chunk loop rolled (code size); register prefetch covers latency
  for (int c = 0; c < 4; ++c) {
    float4 n0, n1, n2, n3;  // next sigma chunk prefetch
    if (c < 3) {
      const float4* gn = g4 + (c + 1) * 1024;
      n0 = gn[tid]; n1 = gn[256 + tid]; n2 = gn[512 + tid]; n3 = gn[768 + tid];
    }
    const int kbase = c * KC;
#pragma unroll
    for (int kk = 0; kk < KC; kk += 4) {
      float4 a0 = *reinterpret_cast<const float4*>(arow0 + kbase + kk);
      float4 a1 = *reinterpret_cast<const float4*>(arow1 + kbase + kk);
      float4 a2 = *reinterpret_cast<const float4*>(arow2 + kbase + kk);
      float4 a3 = *reinterpret_cast<const float4*>(arow3 + kbase + kk);
      QF_STEP(0, a0.x, a1.x, a2.x, a3.x)
      QF_STEP(1, a0.y, a1.y, a2.y, a3.y)
      QF_STEP(2, a0.z, a1.z, a2.z, a3.z)
      QF_STEP(3, a0.w, a1.w, a2.w, a3.w)
    }
    __syncthreads();  // all reads of sig_lds complete
    if (c < 3) {
      float4* sdst = reinterpret_cast<float4*>(&sig_lds[tid * 4]);
      sdst[0] = n0; sdst[256] = n1; sdst[512] = n2; sdst[768] = n3;
      __syncthreads();  // next chunk ready
    }
  }

  // ---- epilogue: score[p] = -sum_l t[p,l]*s[p,l], p = ty + 16*i ----
  float p0s, p1s, p2s, p3s;
  {
    float4 s0 = *reinterpret_cast<const float4*>(arow0 + l0);
    float4 s1 = *reinterpret_cast<const float4*>(arow0 + l0 + 64);
    p0s = acc0l.x*s0.x + acc0l.y*s0.y + acc0l.z*s0.z + acc0l.w*s0.w
        + acc0h.x*s1.x + acc0h.y*s1.y + acc0h.z*s1.z + acc0h.w*s1.w;
    s0 = *reinterpret_cast<const float4*>(arow1 + l0);
    s1 = *reinterpret_cast<const float4*>(arow1 + l0 + 64);
    p1s = acc1l.x*s0.x + acc1l.y*s0.y + acc1l.z*s0.z + acc1l.w*s0.w
        + acc1h.x*s1.x + acc1h.y*s1.y + acc1h.z*s1.z + acc1h.w*s1.w;
    s0 = *reinterpret_cast<const float4*>(arow2 + l0);
    s1 = *reinterpret_cast<const float4*>(arow2 + l0 + 64);
    p2s = acc2l.x*s0.x + acc2l.y*s0.y + acc2l.z*s0.z + acc2l.w*s0.w
        + acc2h.x*s1.x + acc2h.y*s1.y + acc2h.z*s1.z + acc2h.w*s1.w;
    s0 = *reinterpret_cast<const float4*>(arow3 + l0);
    s1 = *reinterpret_cast<const float4*>(arow3 + l0 + 64);
    p3s = acc3l.x*s0.x + acc3l.y*s0.y + acc3l.z*s0.z + acc3l.w*s0.w
        + acc3h.x*s1.x + acc3h.y*s1.y + acc3h.z*s1.z + acc3h.w*s1.w;
  }
  // reduce across the 16 tx-lanes sharing each p (contiguous lanes in a wave)
#pragma unroll
  for (int off = 1; off < 16; off <<= 1) {
    p0s += __shfl_xor(p0s, off, 64);
    p1s += __shfl_xor(p1s, off, 64);
    p2s += __shfl_xor(p2s, off, 64);
    p3s += __shfl_xor(p3s, off, 64);
  }
  if (tx == 0) {
    scores_lds[ty     ] = -p0s;
    scores_lds[ty + 16] = -p1s;
    scores_lds[ty + 32] = -p2s;
    scores_lds[ty + 48] = -p3s;
  }
  __syncthreads();

  // ---- softmax over the 64 scores (single wave) ----
  if (tid < 64) {
    float sc = scores_lds[tid];
    float mx = sc;
#pragma unroll
    for (int off = 1; off < 64; off <<= 1) mx = fmaxf(mx, __shfl_xor(mx, off, 64));
    float e = __expf(sc - mx);
    float s = e;
#pragma unroll
    for (int off = 1; off < 64; off <<= 1) s += __shfl_xor(s, off, 64);
    out[(size_t)m * PP + tid] = e / s;
  }
}

extern "C" void kernel_launch(void* const* d_in, const int* in_sizes, int n_in,
                              void* d_out, int out_size, void* d_ws, size_t ws_size,
                              hipStream_t stream) {
  const float* color = (const float*)d_in[0];   // (M,64,128) fp32
  const float* mew   = (const float*)d_in[1];   // (M,128)    fp32
  const float* sigma = (const float*)d_in[2];   // (M,128,128) fp32
  float* out = (float*)d_out;                   // (M,64) fp32
  const int M = in_sizes[1] / KD;
  quadform_softmax<<<M, 256, 0, stream>>>(color, mew, sigma, out);
}

// Round 5
// 492.390 us; speedup vs baseline: 3.0588x; 2.9463x over previous
//
#include <hip/hip_runtime.h>

#define SROW 132   // padded row stride (mult of 4 -> b128-aligned broadcasts)

// Wave-autonomous quadratic form + softmax.
// Block = 4 waves = one m. Wave w owns p-rows [16w,16w+16).
// score[p] = -(c[p]-mu) Sigma (c[p]-mu)^T, softmax over p in [0,64).
//
// Rounds 2-4 postmortem: block-wide LDS staging structure carried an invariant
// ~4.8 GB/dispatch of HBM traffic (12x demand) regardless of codegen. This
// version has NO barriers in the hot path, NO sigma LDS staging (streamed
// through named float2 regs), per-wave-private shifted rows in LDS read only
// via same-address broadcasts, and 32 named accumulator floats (no arrays).

__global__ __launch_bounds__(256, 4)
void quadform_softmax(const float* __restrict__ color,
                      const float* __restrict__ mew,
                      const float* __restrict__ sigma,
                      float* __restrict__ out) {
  __shared__ __align__(16) float s_all[4 * 16 * SROW];  // 33792 B, per-wave segments
  __shared__ float scores_lds[64];

  const int tid = threadIdx.x;
  const int wv = tid >> 6;
  const int lane = tid & 63;
  const int m = blockIdx.x;

  float* sw = &s_all[wv * (16 * SROW)];

  // ---- stage shifted rows [16wv, 16wv+16) into this wave's private segment ----
  {
    const int h = lane >> 5;        // 0/1: even/odd rows
    const int q = lane & 31;        // col quad
    const float4* c4 = reinterpret_cast<const float4*>(color + (size_t)m * 8192)
                       + (size_t)(16 * wv) * 32;
    const float4 mw = reinterpret_cast<const float4*>(mew + (size_t)m * 128)[q];
#pragma unroll
    for (int r = 0; r < 8; ++r) {
      const int row = h + 2 * r;
      float4 v = c4[row * 32 + q];
      v.x -= mw.x; v.y -= mw.y; v.z -= mw.z; v.w -= mw.w;
      *reinterpret_cast<float4*>(&sw[row * SROW + 4 * q]) = v;
    }
  }
  // wave-local write->read: compiler's lgkmcnt ordering suffices; NO barrier.

  // ---- stream sigma rows; rank-1 accumulate t[p, 2*lane .. 2*lane+1] ----
  const float2* g2 = reinterpret_cast<const float2*>(sigma + (size_t)m * 16384);

  float2 c0 = g2[lane], c1 = g2[64 + lane], c2 = g2[128 + lane], c3 = g2[192 + lane];

  float2 a0 = {0,0}, a1 = {0,0}, a2 = {0,0}, a3 = {0,0};
  float2 a4 = {0,0}, a5 = {0,0}, a6 = {0,0}, a7 = {0,0};
  float2 a8 = {0,0}, a9 = {0,0}, a10 = {0,0}, a11 = {0,0};
  float2 a12 = {0,0}, a13 = {0,0}, a14 = {0,0}, a15 = {0,0};

#pragma unroll 1
  for (int kb = 0; kb < 128; kb += 4) {
    float2 n0, n1, n2, n3;
    const bool more = (kb < 124);
    if (more) {
      const float2* gn = g2 + (size_t)(kb + 4) * 64;
      n0 = gn[lane]; n1 = gn[64 + lane]; n2 = gn[128 + lane]; n3 = gn[192 + lane];
    }
    // s[p, kb..kb+3] broadcast (same address across the wave -> conflict-free)
#define QP(i)                                                               \
    {                                                                       \
      float4 sb = *reinterpret_cast<const float4*>(&sw[(i) * SROW + kb]);   \
      a##i.x = fmaf(sb.x, c0.x, a##i.x); a##i.y = fmaf(sb.x, c0.y, a##i.y); \
      a##i.x = fmaf(sb.y, c1.x, a##i.x); a##i.y = fmaf(sb.y, c1.y, a##i.y); \
      a##i.x = fmaf(sb.z, c2.x, a##i.x); a##i.y = fmaf(sb.z, c2.y, a##i.y); \
      a##i.x = fmaf(sb.w, c3.x, a##i.x); a##i.y = fmaf(sb.w, c3.y, a##i.y); \
    }
    QP(0) QP(1) QP(2) QP(3) QP(4) QP(5) QP(6) QP(7)
    QP(8) QP(9) QP(10) QP(11) QP(12) QP(13) QP(14) QP(15)
#undef QP
    if (more) { c0 = n0; c1 = n1; c2 = n2; c3 = n3; }
  }

  // ---- epilogue: score[p] = -sum_l t[p,l] s[p,l]; full-wave butterfly per p ----
#define RED(i)                                                                   \
  {                                                                              \
    float2 sv = *reinterpret_cast<const float2*>(&sw[(i) * SROW + 2 * lane]);    \
    float part = a##i.x * sv.x + a##i.y * sv.y;                                  \
    part += __shfl_xor(part, 1, 64);  part += __shfl_xor(part, 2, 64);           \
    part += __shfl_xor(part, 4, 64);  part += __shfl_xor(part, 8, 64);           \
    part += __shfl_xor(part, 16, 64); part += __shfl_xor(part, 32, 64);          \
    if (lane == (i)) scores_lds[wv * 16 + (i)] = -part;                          \
  }
  RED(0) RED(1) RED(2) RED(3) RED(4) RED(5) RED(6) RED(7)
  RED(8) RED(9) RED(10) RED(11) RED(12) RED(13) RED(14) RED(15)
#undef RED
  __syncthreads();  // the ONLY block barrier

  // ---- softmax over the 64 scores (single wave) ----
  if (tid < 64) {
    float sc = scores_lds[tid];
    float mx = sc;
#pragma unroll
    for (int off = 1; off < 64; off <<= 1) mx = fmaxf(mx, __shfl_xor(mx, off, 64));
    float e = __expf(sc - mx);
    float s = e;
#pragma unroll
    for (int off = 1; off < 64; off <<= 1) s += __shfl_xor(s, off, 64);
    out[(size_t)m * 64 + tid] = e / s;
  }
}

extern "C" void kernel_launch(void* const* d_in, const int* in_sizes, int n_in,
                              void* d_out, int out_size, void* d_ws, size_t ws_size,
                              hipStream_t stream) {
  const float* color = (const float*)d_in[0];   // (M,64,128) fp32
  const float* mew   = (const float*)d_in[1];   // (M,128)    fp32
  const float* sigma = (const float*)d_in[2];   // (M,128,128) fp32
  float* out = (float*)d_out;                   // (M,64) fp32
  const int M = in_sizes[1] / 128;
  quadform_softmax<<<M, 256, 0, stream>>>(color, mew, sigma, out);
}